// Round 1
// baseline (460.775 us; speedup 1.0000x reference)
//
#include <hip/hip_runtime.h>

#define B_ 4
#define N_ 2048
#define D_ 512
#define H_ 8
#define S_ (N_ + 1)          // 2049
#define SCHUNK 64
#define NCHUNK ((S_ + SCHUNK - 1) / SCHUNK)   // 33

// workspace layout (float offsets)
#define TQ_OFF   0                         // [H][D] folded query  (4096)
#define C_OFF    4096                      // [H] bias term        (8)
#define ATTN_OFF 8192                      // [B*H][S] scores/attn (65568)
#define PW_OFF   81920                     // [NCHUNK][B*H*D] partial weighted sums
#define W_OFF    (PW_OFF + NCHUNK * B_ * H_ * D_)   // [B*H*D] weighted sums

__device__ __forceinline__ float wave_reduce_sum(float v) {
    #pragma unroll
    for (int off = 32; off > 0; off >>= 1) v += __shfl_down(v, off, 64);
    return v;
}

// ---- Kernel A: q0 = Wq*ct + bq; tq[h,j] = sum_{d in head h} q0[d]*Wk[d,j]; c[h] = q0_h . bk_h
__global__ void precompute_kernel(const float* __restrict__ ct,
                                  const float* __restrict__ Wq, const float* __restrict__ bq,
                                  const float* __restrict__ Wk, const float* __restrict__ bk,
                                  float* __restrict__ ws) {
    __shared__ float ct_sh[D_];
    __shared__ float q0_sh[D_];
    int tid = threadIdx.x;               // 512 threads
    ct_sh[tid] = ct[tid];
    __syncthreads();
    int wv = tid >> 6, lane = tid & 63;
    const float4* ct4 = (const float4*)ct_sh;
    float4 ca = ct4[lane * 2], cb = ct4[lane * 2 + 1];
    for (int rr = 0; rr < 64; ++rr) {
        int r = wv * 64 + rr;
        const float4* row = (const float4*)(Wq + (size_t)r * D_);
        float4 a = row[lane * 2], b = row[lane * 2 + 1];
        float acc = a.x*ca.x + a.y*ca.y + a.z*ca.z + a.w*ca.w
                  + b.x*cb.x + b.y*cb.y + b.z*cb.z + b.w*cb.w;
        acc = wave_reduce_sum(acc);
        if (lane == 0) q0_sh[r] = acc + bq[r];
    }
    __syncthreads();
    int j = tid;
    #pragma unroll 1
    for (int h = 0; h < H_; ++h) {
        float acc = 0.f;
        for (int d2 = 0; d2 < 64; ++d2)
            acc += q0_sh[h * 64 + d2] * Wk[(size_t)(h * 64 + d2) * D_ + j];
        ws[TQ_OFF + h * D_ + j] = acc;
    }
    if (tid < H_) {
        float acc = 0.f;
        for (int d2 = 0; d2 < 64; ++d2) acc += q0_sh[tid * 64 + d2] * bk[tid * 64 + d2];
        ws[C_OFF + tid] = acc;
    }
}

// ---- Kernel B: scores[b,h,s] = (tq[h] . x_s + c[h]) / 8, masked where masks==0
__global__ void scores_kernel(const float* __restrict__ nf, const float* __restrict__ ct,
                              const float* __restrict__ masks, float* __restrict__ ws) {
    int b = blockIdx.y;
    int wv = threadIdx.x >> 6, lane = threadIdx.x & 63;
    int s = blockIdx.x * 4 + wv;
    if (s >= S_) return;
    const float* xrow = (s == 0) ? ct : (nf + ((size_t)b * N_ + (s - 1)) * D_);
    const float4* x4 = (const float4*)xrow;
    float4 xa = x4[lane];        // j = 4*lane .. +3      (0..255)
    float4 xb = x4[64 + lane];   // j = 256 + 4*lane ..   (256..511)
    bool masked = (s > 0) && (masks[b * N_ + (s - 1)] == 0.0f);
    const float* tq = ws + TQ_OFF;
    #pragma unroll
    for (int h = 0; h < H_; ++h) {
        const float4* t4 = (const float4*)(tq + h * D_);
        float4 ta = t4[lane], tb = t4[64 + lane];
        float acc = ta.x*xa.x + ta.y*xa.y + ta.z*xa.z + ta.w*xa.w
                  + tb.x*xb.x + tb.y*xb.y + tb.z*xb.z + tb.w*xb.w;
        acc = wave_reduce_sum(acc);
        if (lane == 0) {
            float sc = (acc + ws[C_OFF + h]) * 0.125f;
            if (masked) sc = -1e9f;
            ws[ATTN_OFF + (size_t)(b * H_ + h) * S_ + s] = sc;
        }
    }
}

// ---- Kernel C: softmax over S per (b,h), in place
__global__ void softmax_kernel(float* __restrict__ ws) {
    int bh = blockIdx.x;                    // 0..31
    float* sc = ws + ATTN_OFF + (size_t)bh * S_;
    int tid = threadIdx.x, wv = tid >> 6, lane = tid & 63;
    __shared__ float red[4];
    float m = -3e38f;
    for (int i = tid; i < S_; i += 256) m = fmaxf(m, sc[i]);
    #pragma unroll
    for (int off = 32; off > 0; off >>= 1) m = fmaxf(m, __shfl_down(m, off, 64));
    if (lane == 0) red[wv] = m;
    __syncthreads();
    m = fmaxf(fmaxf(red[0], red[1]), fmaxf(red[2], red[3]));
    __syncthreads();
    float sum = 0.f;
    for (int i = tid; i < S_; i += 256) { float e = __expf(sc[i] - m); sc[i] = e; sum += e; }
    sum = wave_reduce_sum(sum);
    if (lane == 0) red[wv] = sum;
    __syncthreads();
    float inv = 1.0f / (red[0] + red[1] + red[2] + red[3]);
    for (int i = tid; i < S_; i += 256) sc[i] *= inv;
}

// ---- Kernel D: partial weighted sums pw[chunk][b,h,j] = sum_{s in chunk} attn[b,h,s]*x_s[j]
__global__ void wsum_kernel(const float* __restrict__ nf, const float* __restrict__ ct,
                            float* __restrict__ ws) {
    int chunk = blockIdx.x;       // 0..NCHUNK-1
    int jc = blockIdx.y;          // 0..3
    int b  = blockIdx.z;          // 0..3
    int tid = threadIdx.x;        // 128
    int j = jc * 128 + tid;
    __shared__ float sa[H_][SCHUNK];
    int s0 = chunk * SCHUNK;
    for (int idx = tid; idx < H_ * SCHUNK; idx += 128) {
        int h = idx / SCHUNK, ss = idx % SCHUNK;
        int s = s0 + ss;
        sa[h][ss] = (s < S_) ? ws[ATTN_OFF + (size_t)(b * H_ + h) * S_ + s] : 0.f;
    }
    __syncthreads();
    float acc[H_];
    #pragma unroll
    for (int h = 0; h < H_; ++h) acc[h] = 0.f;
    int smax = min(SCHUNK, S_ - s0);
    for (int ss = 0; ss < smax; ++ss) {
        int s = s0 + ss;
        float xv = (s == 0) ? ct[j] : nf[((size_t)b * N_ + (s - 1)) * D_ + j];
        #pragma unroll
        for (int h = 0; h < H_; ++h) acc[h] += sa[h][ss] * xv;
    }
    size_t base = (size_t)chunk * (B_ * H_ * D_) + (size_t)(b * H_) * D_ + j;
    #pragma unroll
    for (int h = 0; h < H_; ++h)
        ws[PW_OFF + base + (size_t)h * D_] = acc[h];
}

// ---- Kernel E: reduce partials -> w[b,h,j]
__global__ void reduce_w_kernel(float* __restrict__ ws) {
    int idx = blockIdx.x * 256 + threadIdx.x;   // < B*H*D = 16384
    float acc = 0.f;
    #pragma unroll 1
    for (int c = 0; c < NCHUNK; ++c) acc += ws[PW_OFF + (size_t)c * (B_ * H_ * D_) + idx];
    ws[W_OFF + idx] = acc;
}

// ---- Kernel F: out0 = Wv*w + bv (per head slice); proj = Wo*out0 + bo; +ct; layernorm
__global__ void final_kernel(const float* __restrict__ ct,
                             const float* __restrict__ Wv, const float* __restrict__ bv,
                             const float* __restrict__ Wo, const float* __restrict__ bo,
                             const float* __restrict__ gamma, const float* __restrict__ beta,
                             const float* __restrict__ ws, float* __restrict__ out) {
    int b = blockIdx.x;
    int tid = threadIdx.x;        // 512
    int wv = tid >> 6, lane = tid & 63;
    __shared__ float w_sh[H_ * D_];
    __shared__ float o0_sh[D_];
    __shared__ float y_sh[D_];
    for (int idx = tid; idx < H_ * D_; idx += 512) w_sh[idx] = ws[W_OFF + b * H_ * D_ + idx];
    __syncthreads();
    // phase 1: out0[r] = Wv[r,:] . w[b, r/64, :] + bv[r]   (rows of wave wv are all head wv)
    {
        const float4* wsv = (const float4*)(w_sh + wv * D_);
        float4 wa = wsv[lane * 2], wb = wsv[lane * 2 + 1];
        for (int rr = 0; rr < 64; ++rr) {
            int r = wv * 64 + rr;
            const float4* row = (const float4*)(Wv + (size_t)r * D_);
            float4 a = row[lane * 2], c = row[lane * 2 + 1];
            float acc = a.x*wa.x + a.y*wa.y + a.z*wa.z + a.w*wa.w
                      + c.x*wb.x + c.y*wb.y + c.z*wb.z + c.w*wb.w;
            acc = wave_reduce_sum(acc);
            if (lane == 0) o0_sh[r] = acc + bv[r];
        }
    }
    __syncthreads();
    // phase 2: y[r] = Wo[r,:] . out0 + bo[r] + ct[r]
    {
        const float4* ov = (const float4*)o0_sh;
        float4 oa = ov[lane * 2], ob = ov[lane * 2 + 1];
        for (int rr = 0; rr < 64; ++rr) {
            int r = wv * 64 + rr;
            const float4* row = (const float4*)(Wo + (size_t)r * D_);
            float4 a = row[lane * 2], c = row[lane * 2 + 1];
            float acc = a.x*oa.x + a.y*oa.y + a.z*oa.z + a.w*oa.w
                      + c.x*ob.x + c.y*ob.y + c.z*ob.z + c.w*ob.w;
            acc = wave_reduce_sum(acc);
            if (lane == 0) y_sh[r] = acc + bo[r] + ct[r];
        }
    }
    __syncthreads();
    // phase 3: layernorm over D
    float v = y_sh[tid];
    float s1 = v, s2 = v * v;
    #pragma unroll
    for (int off = 32; off > 0; off >>= 1) {
        s1 += __shfl_down(s1, off, 64);
        s2 += __shfl_down(s2, off, 64);
    }
    __shared__ float r1[8], r2[8];
    if (lane == 0) { r1[wv] = s1; r2[wv] = s2; }
    __syncthreads();
    if (tid == 0) {
        float a = 0.f, c = 0.f;
        for (int i = 0; i < 8; ++i) { a += r1[i]; c += r2[i]; }
        r1[0] = a; r2[0] = c;
    }
    __syncthreads();
    float mean = r1[0] * (1.0f / D_);
    float var  = r2[0] * (1.0f / D_) - mean * mean;
    float rinv = rsqrtf(var + 1e-5f);
    out[b * D_ + tid] = (v - mean) * rinv * gamma[tid] + beta[tid];
}

extern "C" void kernel_launch(void* const* d_in, const int* in_sizes, int n_in,
                              void* d_out, int out_size, void* d_ws, size_t ws_size,
                              hipStream_t stream) {
    const float* nf    = (const float*)d_in[0];   // node_feat [B,N,D]
    // d_in[1] edge_weights, d_in[2] adj_matrix: NOT needed for CLS row output
    const float* masks = (const float*)d_in[3];   // [B,N]
    const float* ct    = (const float*)d_in[4];   // [D]
    const float* Wq    = (const float*)d_in[5];
    const float* bq    = (const float*)d_in[6];
    const float* Wk    = (const float*)d_in[7];
    const float* bk    = (const float*)d_in[8];
    const float* Wv    = (const float*)d_in[9];
    const float* bv    = (const float*)d_in[10];
    const float* Wo    = (const float*)d_in[11];
    const float* bo    = (const float*)d_in[12];
    const float* gamma = (const float*)d_in[13];
    const float* beta  = (const float*)d_in[14];
    float* ws  = (float*)d_ws;
    float* out = (float*)d_out;

    hipLaunchKernelGGL(precompute_kernel, dim3(1), dim3(512), 0, stream,
                       ct, Wq, bq, Wk, bk, ws);
    hipLaunchKernelGGL(scores_kernel, dim3((S_ + 3) / 4, B_), dim3(256), 0, stream,
                       nf, ct, masks, ws);
    hipLaunchKernelGGL(softmax_kernel, dim3(B_ * H_), dim3(256), 0, stream, ws);
    hipLaunchKernelGGL(wsum_kernel, dim3(NCHUNK, D_ / 128, B_), dim3(128), 0, stream,
                       nf, ct, ws);
    hipLaunchKernelGGL(reduce_w_kernel, dim3(B_ * H_ * D_ / 256), dim3(256), 0, stream, ws);
    hipLaunchKernelGGL(final_kernel, dim3(B_), dim3(512), 0, stream,
                       ct, Wv, bv, Wo, bo, gamma, beta, ws, out);
}

// Round 2
// 231.987 us; speedup vs baseline: 1.9862x; 1.9862x over previous
//
#include <hip/hip_runtime.h>

#define B_ 4
#define N_ 2048
#define D_ 512
#define H_ 8
#define S_ (N_ + 1)          // 2049
#define SCHUNK 64
#define NCHUNK ((S_ + SCHUNK - 1) / SCHUNK)   // 33

// workspace layout (float offsets)
#define TQ_OFF   0                                   // [H][D] folded query (4096)
#define ATTN_OFF 8192                                // [B*H][S] scores/attn (65568)
#define PW_OFF   81920                               // [NCHUNK][B*H*D] partials
#define W_OFF    (PW_OFF + NCHUNK * B_ * H_ * D_)    // [B*H*D]
#define O0_OFF   (W_OFF + B_ * H_ * D_)              // [B][D]
#define Y_OFF    (O0_OFF + B_ * D_)                  // [B][D]

__device__ __forceinline__ float wave_reduce_sum(float v) {
    #pragma unroll
    for (int off = 32; off > 0; off >>= 1) v += __shfl_down(v, off, 64);
    return v;
}

// ---- Kernel AB: per head h, compute q0_h = (Wq x ct + bq)[h*64..] redundantly,
// then tq[h,j] = sum_d q0_h[d] * Wk[h*64+d, j].  grid(H,2) x 256
__global__ void tq_kernel(const float* __restrict__ ct,
                          const float* __restrict__ Wq, const float* __restrict__ bq,
                          const float* __restrict__ Wk, float* __restrict__ ws) {
    int h = blockIdx.x, jc = blockIdx.y;
    int tid = threadIdx.x, wv = tid >> 6, lane = tid & 63;
    __shared__ float ct_sh[D_];
    __shared__ float q0_sh[64];
    ct_sh[tid] = ct[tid];
    ct_sh[tid + 256] = ct[tid + 256];
    __syncthreads();
    const float4* c4 = (const float4*)ct_sh;
    float4 ca = c4[lane * 2], cb = c4[lane * 2 + 1];
    #pragma unroll 1
    for (int rr = 0; rr < 16; ++rr) {
        int rl = wv * 16 + rr;
        int r = h * 64 + rl;
        const float4* row = (const float4*)(Wq + (size_t)r * D_);
        float4 a = row[lane * 2], b = row[lane * 2 + 1];
        float acc = a.x*ca.x + a.y*ca.y + a.z*ca.z + a.w*ca.w
                  + b.x*cb.x + b.y*cb.y + b.z*cb.z + b.w*cb.w;
        acc = wave_reduce_sum(acc);
        if (lane == 0) q0_sh[rl] = acc + bq[r];
    }
    __syncthreads();
    int j = jc * 256 + tid;
    float acc = 0.f;
    #pragma unroll 4
    for (int d2 = 0; d2 < 64; ++d2)
        acc += q0_sh[d2] * Wk[(size_t)(h * 64 + d2) * D_ + j];
    ws[TQ_OFF + h * D_ + j] = acc;
}

// ---- Kernel C: scores[b,h,s] = (tq[h] . x_s)/8, masked.  (q0.bk const dropped:
// softmax is shift-invariant; -1e9 masked entries underflow to 0 either way.)
__global__ void scores_kernel(const float* __restrict__ nf, const float* __restrict__ ct,
                              const float* __restrict__ masks, float* __restrict__ ws) {
    int b = blockIdx.y;
    int wv = threadIdx.x >> 6, lane = threadIdx.x & 63;
    int s = blockIdx.x * 4 + wv;
    if (s >= S_) return;
    const float* xrow = (s == 0) ? ct : (nf + ((size_t)b * N_ + (s - 1)) * D_);
    const float4* x4 = (const float4*)xrow;
    float4 xa = x4[lane];
    float4 xb = x4[64 + lane];
    bool masked = (s > 0) && (masks[b * N_ + (s - 1)] == 0.0f);
    const float* tq = ws + TQ_OFF;
    #pragma unroll
    for (int h = 0; h < H_; ++h) {
        const float4* t4 = (const float4*)(tq + h * D_);
        float4 ta = t4[lane], tb = t4[64 + lane];
        float acc = ta.x*xa.x + ta.y*xa.y + ta.z*xa.z + ta.w*xa.w
                  + tb.x*xb.x + tb.y*xb.y + tb.z*xb.z + tb.w*xb.w;
        acc = wave_reduce_sum(acc);
        if (lane == 0) {
            float sc = acc * 0.125f;
            if (masked) sc = -1e9f;
            ws[ATTN_OFF + (size_t)(b * H_ + h) * S_ + s] = sc;
        }
    }
}

// ---- Kernel D: softmax over S per (b,h), in place
__global__ void softmax_kernel(float* __restrict__ ws) {
    int bh = blockIdx.x;                    // 0..31
    float* sc = ws + ATTN_OFF + (size_t)bh * S_;
    int tid = threadIdx.x, wv = tid >> 6, lane = tid & 63;
    __shared__ float red[4];
    float m = -3e38f;
    for (int i = tid; i < S_; i += 256) m = fmaxf(m, sc[i]);
    #pragma unroll
    for (int off = 32; off > 0; off >>= 1) m = fmaxf(m, __shfl_down(m, off, 64));
    if (lane == 0) red[wv] = m;
    __syncthreads();
    m = fmaxf(fmaxf(red[0], red[1]), fmaxf(red[2], red[3]));
    __syncthreads();
    float sum = 0.f;
    for (int i = tid; i < S_; i += 256) { float e = __expf(sc[i] - m); sc[i] = e; sum += e; }
    sum = wave_reduce_sum(sum);
    if (lane == 0) red[wv] = sum;
    __syncthreads();
    float inv = 1.0f / (red[0] + red[1] + red[2] + red[3]);
    for (int i = tid; i < S_; i += 256) sc[i] *= inv;
}

// ---- Kernel E: pw[chunk][b,h,j] = sum_{s in chunk} attn[b,h,s]*x_s[j]
// grid(NCHUNK, B) x 128; thread owns 4 consecutive j (float4)
__global__ void wsum_kernel(const float* __restrict__ nf, const float* __restrict__ ct,
                            float* __restrict__ ws) {
    int chunk = blockIdx.x;
    int b = blockIdx.y;
    int tid = threadIdx.x;        // 0..127 -> j4
    __shared__ float sa[H_][SCHUNK];
    int s0 = chunk * SCHUNK;
    for (int idx = tid; idx < H_ * SCHUNK; idx += 128) {
        int h = idx >> 6, ss = idx & 63;
        int s = s0 + ss;
        sa[h][ss] = (s < S_) ? ws[ATTN_OFF + (size_t)(b * H_ + h) * S_ + s] : 0.f;
    }
    __syncthreads();
    float4 acc[H_];
    #pragma unroll
    for (int h = 0; h < H_; ++h) acc[h] = make_float4(0.f, 0.f, 0.f, 0.f);
    int smax = min(SCHUNK, S_ - s0);
    for (int ss = 0; ss < smax; ++ss) {
        int s = s0 + ss;
        const float* xrow = (s == 0) ? ct : (nf + ((size_t)b * N_ + (s - 1)) * D_);
        float4 xv = ((const float4*)xrow)[tid];
        #pragma unroll
        for (int h = 0; h < H_; ++h) {
            float a = sa[h][ss];
            acc[h].x += a * xv.x; acc[h].y += a * xv.y;
            acc[h].z += a * xv.z; acc[h].w += a * xv.w;
        }
    }
    float4* pw = (float4*)(ws + PW_OFF + (size_t)chunk * (B_ * H_ * D_) + (size_t)(b * H_) * D_);
    #pragma unroll
    for (int h = 0; h < H_; ++h)
        pw[h * (D_ / 4) + tid] = acc[h];
}

// ---- Kernel F: reduce partials -> w[b,h,j]   grid(16) x 256, float4
__global__ void reduce_w_kernel(float* __restrict__ ws) {
    int idx = blockIdx.x * 256 + threadIdx.x;   // < B*H*D/4 = 4096
    float4 acc = make_float4(0.f, 0.f, 0.f, 0.f);
    #pragma unroll 1
    for (int c = 0; c < NCHUNK; ++c) {
        float4 v = ((const float4*)(ws + PW_OFF + (size_t)c * (B_ * H_ * D_)))[idx];
        acc.x += v.x; acc.y += v.y; acc.z += v.z; acc.w += v.w;
    }
    ((float4*)(ws + W_OFF))[idx] = acc;
}

// ---- Kernel G: o0[b,r] = Wv[r,:] . w[b, r/64, :] + bv[r]   grid(B,128) x 256
__global__ void wv_kernel(const float* __restrict__ Wv, const float* __restrict__ bv,
                          float* __restrict__ ws) {
    int b = blockIdx.x;
    int wv = threadIdx.x >> 6, lane = threadIdx.x & 63;
    int r = blockIdx.y * 4 + wv;   // 0..511
    const float4* wrow = (const float4*)(ws + W_OFF + (size_t)b * H_ * D_ + (size_t)(r >> 6) * D_);
    float4 wa = wrow[lane * 2], wb = wrow[lane * 2 + 1];
    const float4* row = (const float4*)(Wv + (size_t)r * D_);
    float4 a = row[lane * 2], c = row[lane * 2 + 1];
    float acc = a.x*wa.x + a.y*wa.y + a.z*wa.z + a.w*wa.w
              + c.x*wb.x + c.y*wb.y + c.z*wb.z + c.w*wb.w;
    acc = wave_reduce_sum(acc);
    if (lane == 0) ws[O0_OFF + b * D_ + r] = acc + bv[r];
}

// ---- Kernel H: y[b,r] = Wo[r,:] . o0[b,:] + bo[r] + ct[r]   grid(B,128) x 256
__global__ void wo_kernel(const float* __restrict__ Wo, const float* __restrict__ bo,
                          const float* __restrict__ ct, float* __restrict__ ws) {
    int b = blockIdx.x;
    int wv = threadIdx.x >> 6, lane = threadIdx.x & 63;
    int r = blockIdx.y * 4 + wv;
    const float4* ov = (const float4*)(ws + O0_OFF + (size_t)b * D_);
    float4 oa = ov[lane * 2], ob = ov[lane * 2 + 1];
    const float4* row = (const float4*)(Wo + (size_t)r * D_);
    float4 a = row[lane * 2], c = row[lane * 2 + 1];
    float acc = a.x*oa.x + a.y*oa.y + a.z*oa.z + a.w*oa.w
              + c.x*ob.x + c.y*ob.y + c.z*ob.z + c.w*ob.w;
    acc = wave_reduce_sum(acc);
    if (lane == 0) ws[Y_OFF + b * D_ + r] = acc + bo[r] + ct[r];
}

// ---- Kernel I: layernorm over D per batch   grid(B) x 512
__global__ void ln_kernel(const float* __restrict__ gamma, const float* __restrict__ beta,
                          const float* __restrict__ ws, float* __restrict__ out) {
    int b = blockIdx.x;
    int tid = threadIdx.x, wv = tid >> 6, lane = tid & 63;
    float v = ws[Y_OFF + b * D_ + tid];
    float s1 = v, s2 = v * v;
    #pragma unroll
    for (int off = 32; off > 0; off >>= 1) {
        s1 += __shfl_down(s1, off, 64);
        s2 += __shfl_down(s2, off, 64);
    }
    __shared__ float r1[8], r2[8];
    if (lane == 0) { r1[wv] = s1; r2[wv] = s2; }
    __syncthreads();
    if (tid == 0) {
        float a = 0.f, c = 0.f;
        for (int i = 0; i < 8; ++i) { a += r1[i]; c += r2[i]; }
        r1[0] = a; r2[0] = c;
    }
    __syncthreads();
    float mean = r1[0] * (1.0f / D_);
    float var  = r2[0] * (1.0f / D_) - mean * mean;
    float rinv = rsqrtf(var + 1e-5f);
    out[b * D_ + tid] = (v - mean) * rinv * gamma[tid] + beta[tid];
}

extern "C" void kernel_launch(void* const* d_in, const int* in_sizes, int n_in,
                              void* d_out, int out_size, void* d_ws, size_t ws_size,
                              hipStream_t stream) {
    const float* nf    = (const float*)d_in[0];   // node_feat [B,N,D]
    // d_in[1] edge_weights, d_in[2] adj_matrix: not needed for CLS-row output
    const float* masks = (const float*)d_in[3];   // [B,N]
    const float* ct    = (const float*)d_in[4];   // [D]
    const float* Wq    = (const float*)d_in[5];
    const float* bq    = (const float*)d_in[6];
    const float* Wk    = (const float*)d_in[7];
    // d_in[8] bk: dropped (softmax shift-invariance)
    const float* Wv    = (const float*)d_in[9];
    const float* bv    = (const float*)d_in[10];
    const float* Wo    = (const float*)d_in[11];
    const float* bo    = (const float*)d_in[12];
    const float* gamma = (const float*)d_in[13];
    const float* beta  = (const float*)d_in[14];
    float* ws  = (float*)d_ws;
    float* out = (float*)d_out;

    hipLaunchKernelGGL(tq_kernel, dim3(H_, 2), dim3(256), 0, stream,
                       ct, Wq, bq, Wk, ws);
    hipLaunchKernelGGL(scores_kernel, dim3((S_ + 3) / 4, B_), dim3(256), 0, stream,
                       nf, ct, masks, ws);
    hipLaunchKernelGGL(softmax_kernel, dim3(B_ * H_), dim3(256), 0, stream, ws);
    hipLaunchKernelGGL(wsum_kernel, dim3(NCHUNK, B_), dim3(128), 0, stream,
                       nf, ct, ws);
    hipLaunchKernelGGL(reduce_w_kernel, dim3(16), dim3(256), 0, stream, ws);
    hipLaunchKernelGGL(wv_kernel, dim3(B_, 128), dim3(256), 0, stream, Wv, bv, ws);
    hipLaunchKernelGGL(wo_kernel, dim3(B_, 128), dim3(256), 0, stream, Wo, bo, ct, ws);
    hipLaunchKernelGGL(ln_kernel, dim3(B_), dim3(512), 0, stream, gamma, beta, ws, out);
}